// Round 1
// baseline (1992.014 us; speedup 1.0000x reference)
//
#include <hip/hip_runtime.h>

// Problem: x (8,2048,512) f32, embed (1,8192,512) f32 (rows unit-norm).
// dist[r][c] = dot(x_row[r], embed[c])  -> (16384, 8192)
// ind[r] = argmax_c dist[r][c]
// outputs (concat f32): quantize = embed[ind] (8*2048*512) | ind as float (16384) | dist (16384*8192)

#define BM 128
#define BN 128
#define BK 16
#define TM 8
#define TN 8
#define KDIM 512
#define NROWS 16384
#define NCOLS 8192
#define NCTILES (NCOLS / BN)   // 64

// ---------------- kernel 1: GEMM + per-(row, col-tile) argmax ----------------
__global__ __launch_bounds__(256, 2) void gemm_argmax_kernel(
    const float* __restrict__ x,       // [16384,512]
    const float* __restrict__ embed,   // [8192,512]
    float* __restrict__ dist,          // [16384,8192]
    float* __restrict__ ws_val,        // [16384*64]
    int*   __restrict__ ws_idx)        // [16384*64]
{
    __shared__ float As[BK][BM + 4];
    __shared__ float Bs[BK][BN + 4];
    __shared__ float redV[BM * 16];
    __shared__ int   redI[BM * 16];

    const int tid = threadIdx.x;
    const int tx  = tid & 15;          // col group
    const int ty  = tid >> 4;          // row group
    const int rowBase = blockIdx.y * BM;
    const int colBase = blockIdx.x * BN;

    // global->LDS load mapping: 128 rows x 16 k-floats = 512 float4 chunks; 256 thr x 2
    const int lrow = tid >> 2;         // 0..63
    const int lc   = tid & 3;          // float4 chunk (4 k-floats)

    const float* Aptr = x     + (size_t)(rowBase + lrow) * KDIM + lc * 4;
    const float* Bptr = embed + (size_t)(colBase + lrow) * KDIM + lc * 4;

    float acc[TM][TN];
#pragma unroll
    for (int i = 0; i < TM; i++)
#pragma unroll
        for (int j = 0; j < TN; j++) acc[i][j] = 0.0f;

    for (int kb = 0; kb < KDIM; kb += BK) {
        // issue global loads early (overlap with prior compute tail)
        const float4 a0 = *(const float4*)(Aptr + kb);
        const float4 a1 = *(const float4*)(Aptr + kb + (size_t)64 * KDIM);
        const float4 b0 = *(const float4*)(Bptr + kb);
        const float4 b1 = *(const float4*)(Bptr + kb + (size_t)64 * KDIM);

        __syncthreads();   // prior iteration finished reading LDS

        const int k0 = lc * 4;
        As[k0 + 0][lrow] = a0.x; As[k0 + 1][lrow] = a0.y;
        As[k0 + 2][lrow] = a0.z; As[k0 + 3][lrow] = a0.w;
        As[k0 + 0][lrow + 64] = a1.x; As[k0 + 1][lrow + 64] = a1.y;
        As[k0 + 2][lrow + 64] = a1.z; As[k0 + 3][lrow + 64] = a1.w;
        Bs[k0 + 0][lrow] = b0.x; Bs[k0 + 1][lrow] = b0.y;
        Bs[k0 + 2][lrow] = b0.z; Bs[k0 + 3][lrow] = b0.w;
        Bs[k0 + 0][lrow + 64] = b1.x; Bs[k0 + 1][lrow + 64] = b1.y;
        Bs[k0 + 2][lrow + 64] = b1.z; Bs[k0 + 3][lrow + 64] = b1.w;

        __syncthreads();

#pragma unroll
        for (int k = 0; k < BK; k++) {
            const float4 av0 = *(const float4*)&As[k][ty * TM];
            const float4 av1 = *(const float4*)&As[k][ty * TM + 4];
            const float4 bv0 = *(const float4*)&Bs[k][tx * TN];
            const float4 bv1 = *(const float4*)&Bs[k][tx * TN + 4];
            const float a[TM] = {av0.x, av0.y, av0.z, av0.w, av1.x, av1.y, av1.z, av1.w};
            const float b[TN] = {bv0.x, bv0.y, bv0.z, bv0.w, bv1.x, bv1.y, bv1.z, bv1.w};
#pragma unroll
            for (int i = 0; i < TM; i++)
#pragma unroll
                for (int j = 0; j < TN; j++)
                    acc[i][j] = fmaf(a[i], b[j], acc[i][j]);
        }
    }

    // ---- write dist tile (coalesced float4) ----
#pragma unroll
    for (int i = 0; i < TM; i++) {
        const int r = rowBase + ty * TM + i;
        float4* p = (float4*)(dist + (size_t)r * NCOLS + colBase + tx * TN);
        p[0] = make_float4(acc[i][0], acc[i][1], acc[i][2], acc[i][3]);
        p[1] = make_float4(acc[i][4], acc[i][5], acc[i][6], acc[i][7]);
    }

    // ---- per-thread per-row max over its 8 cols (ascending j, strict > => lowest idx on tie) ----
#pragma unroll
    for (int i = 0; i < TM; i++) {
        float bv = acc[i][0];
        int   bj = 0;
#pragma unroll
        for (int j = 1; j < TN; j++)
            if (acc[i][j] > bv) { bv = acc[i][j]; bj = j; }
        const int lrowi = ty * TM + i;
        redV[lrowi * 16 + tx] = bv;
        redI[lrowi * 16 + tx] = colBase + tx * TN + bj;
    }
    __syncthreads();

    // ---- 128 threads reduce 16 entries/row (ascending tx => lowest idx on tie) ----
    if (tid < BM) {
        float bv = redV[tid * 16];
        int   bi = redI[tid * 16];
#pragma unroll
        for (int t = 1; t < 16; t++) {
            const float v = redV[tid * 16 + t];
            if (v > bv) { bv = v; bi = redI[tid * 16 + t]; }
        }
        const int r = rowBase + tid;
        ws_val[(size_t)r * NCTILES + blockIdx.x] = bv;
        ws_idx[(size_t)r * NCTILES + blockIdx.x] = bi;
    }
}

// ---------------- kernel 2: final argmax across 64 tiles + gather ----------------
__global__ __launch_bounds__(64) void finalize_kernel(
    const float* __restrict__ ws_val,
    const int*   __restrict__ ws_idx,
    const float* __restrict__ embed,
    float* __restrict__ out_q,     // [16384*512]
    float* __restrict__ out_ind)   // [16384]
{
    const int r    = blockIdx.x;
    const int lane = threadIdx.x;

    float v = ws_val[(size_t)r * NCTILES + lane];
    int   i = ws_idx[(size_t)r * NCTILES + lane];

    // wave-64 argmax reduce; on tie prefer lower index (matches numpy argmax)
#pragma unroll
    for (int off = 32; off > 0; off >>= 1) {
        const float ov = __shfl_down(v, off);
        const int   oi = __shfl_down(i, off);
        if (ov > v || (ov == v && oi < i)) { v = ov; i = oi; }
    }
    i = __shfl(i, 0);

    if (lane == 0) out_ind[r] = (float)i;

    // gather codebook row: 512 floats = 128 float4, 64 lanes x 2
    const float4* src = (const float4*)(embed + (size_t)i * KDIM);
    float4*       dst = (float4*)(out_q + (size_t)r * KDIM);
    dst[lane]      = src[lane];
    dst[lane + 64] = src[lane + 64];
}

extern "C" void kernel_launch(void* const* d_in, const int* in_sizes, int n_in,
                              void* d_out, int out_size, void* d_ws, size_t ws_size,
                              hipStream_t stream) {
    const float* x     = (const float*)d_in[0];   // 8*2048*512
    const float* embed = (const float*)d_in[1];   // 8192*512

    float* out     = (float*)d_out;
    float* out_q   = out;                              // 8,388,608
    float* out_ind = out + (size_t)8 * 2048 * 512;     // 16,384
    float* dist    = out_ind + NROWS;                  // 134,217,728

    float* ws_val = (float*)d_ws;                                  // 4 MB
    int*   ws_idx = (int*)((char*)d_ws + (size_t)NROWS * NCTILES * sizeof(float)); // 4 MB

    dim3 grid(NCOLS / BN, NROWS / BM);   // (64, 128) = 8192 WGs
    gemm_argmax_kernel<<<grid, dim3(256), 0, stream>>>(x, embed, dist, ws_val, ws_idx);
    finalize_kernel<<<dim3(NROWS), dim3(64), 0, stream>>>(ws_val, ws_idx, embed, out_q, out_ind);
}